// Round 1
// baseline (959.704 us; speedup 1.0000x reference)
//
#include <hip/hip_runtime.h>

#define DD 128

__device__ __forceinline__ float sp(float x) {
    // softplus = max(x,0) + log1p(exp(-|x|)); 1+e in (1,2] so __logf is fine
    return fmaxf(x, 0.0f) + __logf(1.0f + __expf(-fabsf(x)));
}

// Y[n,128] = epilogue( act(X[n,128]) @ W.T + bias )
// POST_ACT: Y = act(.)       (used for A and vm)
// RES_ADD : Y = . + R        (residual second step)
// UX_ADD  : Y = . + u * R    (final output, R = x)
template<int POST_ACT, int RES_ADD, int UX_ADD>
__global__ __launch_bounds__(256, 2)
void gemm_act(const float* __restrict__ X,
              const float* __restrict__ W,
              const float* __restrict__ bias,
              const float* __restrict__ R,
              const float* __restrict__ u,
              float* __restrict__ Y,
              int n)
{
    __shared__ float Wt[128][130];   // W transposed: Wt[k][d] = W[d][k]; 130 keeps float2 aligned + breaks conflicts
    __shared__ float bs[128];
    __shared__ float us[128];
    __shared__ float ax[16][128];    // act(X) rows for current 16-atom tile (wave-private 4 rows each)

    const int t = threadIdx.x;

    // stage W transposed (coalesced float4 reads of row-major W)
    for (int i = t; i < 128 * 32; i += 256) {
        const int d  = i >> 5;            // W row
        const int k4 = (i & 31) << 2;     // starting k
        const float4 w = reinterpret_cast<const float4*>(W)[i];
        Wt[k4 + 0][d] = w.x;
        Wt[k4 + 1][d] = w.y;
        Wt[k4 + 2][d] = w.z;
        Wt[k4 + 3][d] = w.w;
    }
    if (t < 128) {
        bs[t] = bias[t];
        if (UX_ADD) us[t] = u[t];
    }
    __syncthreads();

    const int lane = t & 63;
    const int wv   = t >> 6;             // wave 0..3
    const int d0   = lane << 1;          // this lane's 2 output channels
    const int ntiles = (n + 15) >> 4;

    for (int tile = blockIdx.x; tile < ntiles; tile += gridDim.x) {
        const int rbase = (tile << 4) + (wv << 2);

        // stage act(X) for this wave's 4 rows (wave-private region of ax)
        #pragma unroll
        for (int a = 0; a < 4; ++a) {
            const int row = rbase + a;
            float2 xv = make_float2(0.f, 0.f);
            if (row < n) xv = *reinterpret_cast<const float2*>(X + (size_t)row * DD + d0);
            ax[(wv << 2) + a][d0]     = sp(xv.x);
            ax[(wv << 2) + a][d0 + 1] = sp(xv.y);
        }
        __syncthreads();  // cheap vs 32-step inner loop; guarantees LDS visibility

        float acc0[4] = {0.f, 0.f, 0.f, 0.f};
        float acc1[4] = {0.f, 0.f, 0.f, 0.f};

        #pragma unroll 2
        for (int k0 = 0; k0 < 128; k0 += 4) {
            float axr[4][4];
            #pragma unroll
            for (int a = 0; a < 4; ++a)
                *reinterpret_cast<float4*>(axr[a]) =
                    *reinterpret_cast<const float4*>(&ax[(wv << 2) + a][k0]);
            #pragma unroll
            for (int j = 0; j < 4; ++j) {
                const float2 w = *reinterpret_cast<const float2*>(&Wt[k0 + j][d0]);
                #pragma unroll
                for (int a = 0; a < 4; ++a) {
                    acc0[a] = fmaf(axr[a][j], w.x, acc0[a]);
                    acc1[a] = fmaf(axr[a][j], w.y, acc1[a]);
                }
            }
        }

        #pragma unroll
        for (int a = 0; a < 4; ++a) {
            const int row = rbase + a;
            if (row >= n) continue;
            float y0 = acc0[a] + bs[d0];
            float y1 = acc1[a] + bs[d0 + 1];
            if (POST_ACT) { y0 = sp(y0); y1 = sp(y1); }
            if (RES_ADD) {
                const float2 r = *reinterpret_cast<const float2*>(R + (size_t)row * DD + d0);
                y0 += r.x; y1 += r.y;
            }
            if (UX_ADD) {
                const float2 xr = *reinterpret_cast<const float2*>(R + (size_t)row * DD + d0);
                y0 = fmaf(us[d0],     xr.x, y0);
                y1 = fmaf(us[d0 + 1], xr.y, y1);
            }
            *reinterpret_cast<float2*>(Y + (size_t)row * DD + d0) = make_float2(y0, y1);
        }
        __syncthreads();  // keep waves together before restaging ax (paranoia, cheap)
    }
}

// v[idx_i] += A[idx_j] * (g @ Wg.T + bg), one wave per edge
__global__ __launch_bounds__(256)
void edge_kernel(const float* __restrict__ g,
                 const int* __restrict__ idx_i,
                 const int* __restrict__ idx_j,
                 const float* __restrict__ Wg,
                 const float* __restrict__ bg,
                 const float* __restrict__ A,
                 float* __restrict__ v,
                 int E)
{
    __shared__ float Wgt[20][130];   // Wg transposed
    __shared__ float bgs[128];

    const int t = threadIdx.x;
    for (int i = t; i < 128 * 20; i += 256) {
        const int d = i / 20;
        const int k = i - d * 20;
        Wgt[k][d] = Wg[i];
    }
    if (t < 128) bgs[t] = bg[t];
    __syncthreads();

    const int lane = t & 63;
    const int d0 = lane << 1;
    const int wid = ((blockIdx.x << 8) + t) >> 6;
    const int nw  = (gridDim.x << 8) >> 6;

    for (int e = wid; e < E; e += nw) {
        const int ii = idx_i[e];
        const int jj = idx_j[e];

        const float4* g4 = reinterpret_cast<const float4*>(g + (size_t)e * 20);
        float gv[20];
        #pragma unroll
        for (int q = 0; q < 5; ++q) {
            const float4 p = g4[q];   // same-address broadcast across the wave
            gv[q * 4 + 0] = p.x; gv[q * 4 + 1] = p.y;
            gv[q * 4 + 2] = p.z; gv[q * 4 + 3] = p.w;
        }

        float g0 = bgs[d0], g1 = bgs[d0 + 1];
        #pragma unroll
        for (int k = 0; k < 20; ++k) {
            const float2 w = *reinterpret_cast<const float2*>(&Wgt[k][d0]);
            g0 = fmaf(gv[k], w.x, g0);
            g1 = fmaf(gv[k], w.y, g1);
        }

        const float2 aj = *reinterpret_cast<const float2*>(A + (size_t)jj * DD + d0);
        unsafeAtomicAdd(v + (size_t)ii * DD + d0,     aj.x * g0);
        unsafeAtomicAdd(v + (size_t)ii * DD + d0 + 1, aj.y * g1);
    }
}

extern "C" void kernel_launch(void* const* d_in, const int* in_sizes, int n_in,
                              void* d_out, int out_size, void* d_ws, size_t ws_size,
                              hipStream_t stream)
{
    const float* x     = (const float*)d_in[0];
    const float* g     = (const float*)d_in[1];
    const int*   idx_i = (const int*)d_in[2];
    const int*   idx_j = (const int*)d_in[3];
    // d_in[4] = n_atoms (derived from in_sizes instead)
    const float* u     = (const float*)d_in[5];
    const float* Wf    = (const float*)d_in[6];
    const float* bf    = (const float*)d_in[7];
    const float* Wg    = (const float*)d_in[8];
    const float* bg    = (const float*)d_in[9];
    const float* Wj    = (const float*)d_in[10];
    const float* bj    = (const float*)d_in[11];
    const float* Wi    = (const float*)d_in[12];
    const float* bi    = (const float*)d_in[13];
    const float* rw1   = (const float*)d_in[14];
    const float* rb1   = (const float*)d_in[15];
    const float* rw2   = (const float*)d_in[16];
    const float* rb2   = (const float*)d_in[17];

    const int N = in_sizes[0] / DD;   // 50000
    const int E = in_sizes[2];        // 640000
    float* out = (float*)d_out;

    float* A = (float*)d_ws;                  // [N,128] act(act(x)@Wj.T+bj)
    float* v = A + (size_t)N * DD;            // [N,128] accumulator
    float* h = A;                             // reuse A after edge pass

    dim3 blk(256);
    const int GB = 512;   // 2 blocks/CU * 256 CU

    // A = act(act(x) @ Wj.T + bj)
    gemm_act<1,0,0><<<GB, blk, 0, stream>>>(x, Wj, bj, nullptr, nullptr, A, N);
    // v = act(act(x) @ Wi.T + bi)   (= vm; edge pass accumulates on top)
    gemm_act<1,0,0><<<GB, blk, 0, stream>>>(x, Wi, bi, nullptr, nullptr, v, N);
    // v[idx_i] += A[idx_j] * (g @ Wg.T + bg)
    edge_kernel<<<2048, blk, 0, stream>>>(g, idx_i, idx_j, Wg, bg, A, v, E);
    // residual stack
    for (int l = 0; l < 3; ++l) {
        gemm_act<0,0,0><<<GB, blk, 0, stream>>>(v, rw1 + l * DD * DD, rb1 + l * DD,
                                                nullptr, nullptr, h, N);
        gemm_act<0,1,0><<<GB, blk, 0, stream>>>(h, rw2 + l * DD * DD, rb2 + l * DD,
                                                v, nullptr, v, N);
    }
    // out = u*x + act(v) @ Wf.T + bf
    gemm_act<0,0,1><<<GB, blk, 0, stream>>>(v, Wf, bf, x, u, out, N);
}

// Round 2
// 642.537 us; speedup vs baseline: 1.4936x; 1.4936x over previous
//
#include <hip/hip_runtime.h>

#define DD 128

__device__ __forceinline__ float sp(float x) {
    // softplus = max(x,0) + log1p(exp(-|x|)); 1+e in (1,2] so __logf is fine
    return fmaxf(x, 0.0f) + __logf(1.0f + __expf(-fabsf(x)));
}

// Y[n,128] = epilogue( act(X[n,128]) @ W.T + bias )
template<int POST_ACT, int RES_ADD, int UX_ADD>
__global__ __launch_bounds__(256, 2)
void gemm_act(const float* __restrict__ X,
              const float* __restrict__ W,
              const float* __restrict__ bias,
              const float* __restrict__ R,
              const float* __restrict__ u,
              float* __restrict__ Y,
              int n)
{
    __shared__ float Wt[128][130];
    __shared__ float bs[128];
    __shared__ float us[128];
    __shared__ float ax[16][128];

    const int t = threadIdx.x;

    for (int i = t; i < 128 * 32; i += 256) {
        const int d  = i >> 5;
        const int k4 = (i & 31) << 2;
        const float4 w = reinterpret_cast<const float4*>(W)[i];
        Wt[k4 + 0][d] = w.x;
        Wt[k4 + 1][d] = w.y;
        Wt[k4 + 2][d] = w.z;
        Wt[k4 + 3][d] = w.w;
    }
    if (t < 128) {
        bs[t] = bias[t];
        if (UX_ADD) us[t] = u[t];
    }
    __syncthreads();

    const int lane = t & 63;
    const int wv   = t >> 6;
    const int d0   = lane << 1;
    const int ntiles = (n + 15) >> 4;

    for (int tile = blockIdx.x; tile < ntiles; tile += gridDim.x) {
        const int rbase = (tile << 4) + (wv << 2);

        #pragma unroll
        for (int a = 0; a < 4; ++a) {
            const int row = rbase + a;
            float2 xv = make_float2(0.f, 0.f);
            if (row < n) xv = *reinterpret_cast<const float2*>(X + (size_t)row * DD + d0);
            ax[(wv << 2) + a][d0]     = sp(xv.x);
            ax[(wv << 2) + a][d0 + 1] = sp(xv.y);
        }
        __syncthreads();

        float acc0[4] = {0.f, 0.f, 0.f, 0.f};
        float acc1[4] = {0.f, 0.f, 0.f, 0.f};

        #pragma unroll 2
        for (int k0 = 0; k0 < 128; k0 += 4) {
            float axr[4][4];
            #pragma unroll
            for (int a = 0; a < 4; ++a)
                *reinterpret_cast<float4*>(axr[a]) =
                    *reinterpret_cast<const float4*>(&ax[(wv << 2) + a][k0]);
            #pragma unroll
            for (int j = 0; j < 4; ++j) {
                const float2 w = *reinterpret_cast<const float2*>(&Wt[k0 + j][d0]);
                #pragma unroll
                for (int a = 0; a < 4; ++a) {
                    acc0[a] = fmaf(axr[a][j], w.x, acc0[a]);
                    acc1[a] = fmaf(axr[a][j], w.y, acc1[a]);
                }
            }
        }

        #pragma unroll
        for (int a = 0; a < 4; ++a) {
            const int row = rbase + a;
            if (row >= n) continue;
            float y0 = acc0[a] + bs[d0];
            float y1 = acc1[a] + bs[d0 + 1];
            if (POST_ACT) { y0 = sp(y0); y1 = sp(y1); }
            if (RES_ADD) {
                const float2 r = *reinterpret_cast<const float2*>(R + (size_t)row * DD + d0);
                y0 += r.x; y1 += r.y;
            }
            if (UX_ADD) {
                const float2 xr = *reinterpret_cast<const float2*>(R + (size_t)row * DD + d0);
                y0 = fmaf(us[d0],     xr.x, y0);
                y1 = fmaf(us[d0 + 1], xr.y, y1);
            }
            *reinterpret_cast<float2*>(Y + (size_t)row * DD + d0) = make_float2(y0, y1);
        }
        __syncthreads();
    }
}

// ---------- CSR build: histogram, scan, scatter ----------

__global__ __launch_bounds__(256)
void hist_kernel(const int* __restrict__ idx_i, int* __restrict__ cnt, int E)
{
    const int e = blockIdx.x * 256 + threadIdx.x;
    if (e < E) atomicAdd(&cnt[idx_i[e]], 1);
}

// exclusive scan of cnt[0..n) -> off[0..n), single block of 256 threads, 4 items/thread
__global__ __launch_bounds__(256)
void scan_kernel(const int* __restrict__ cnt, int* __restrict__ off, int n)
{
    __shared__ int wsum[4];
    __shared__ int carry_s;
    const int t = threadIdx.x;
    const int lane = t & 63, wv = t >> 6;
    if (t == 0) carry_s = 0;
    __syncthreads();
    for (int base = 0; base < n; base += 1024) {
        const int i0 = base + t * 4;
        const int v0 = (i0 + 0 < n) ? cnt[i0 + 0] : 0;
        const int v1 = (i0 + 1 < n) ? cnt[i0 + 1] : 0;
        const int v2 = (i0 + 2 < n) ? cnt[i0 + 2] : 0;
        const int v3 = (i0 + 3 < n) ? cnt[i0 + 3] : 0;
        const int s = v0 + v1 + v2 + v3;
        int incl = s;
        #pragma unroll
        for (int d = 1; d < 64; d <<= 1) {
            const int y = __shfl_up(incl, d, 64);
            if (lane >= d) incl += y;
        }
        if (lane == 63) wsum[wv] = incl;
        __syncthreads();
        int woff = 0;
        #pragma unroll
        for (int w = 0; w < 4; ++w) if (w < wv) woff += wsum[w];
        const int excl = carry_s + woff + incl - s;
        if (i0 + 0 < n) off[i0 + 0] = excl;
        if (i0 + 1 < n) off[i0 + 1] = excl + v0;
        if (i0 + 2 < n) off[i0 + 2] = excl + v0 + v1;
        if (i0 + 3 < n) off[i0 + 3] = excl + v0 + v1 + v2;
        __syncthreads();
        if (t == 255) carry_s += woff + incl;   // chunk total
        __syncthreads();
    }
}

__global__ __launch_bounds__(256)
void scatter_kernel(const int* __restrict__ idx_i, const int* __restrict__ idx_j,
                    const int* __restrict__ off, int* __restrict__ cnt2,
                    int* __restrict__ se, int* __restrict__ sj, int E)
{
    const int e = blockIdx.x * 256 + threadIdx.x;
    if (e < E) {
        const int i = idx_i[e];
        const int p = off[i] + atomicAdd(&cnt2[i], 1);
        se[p] = e;
        sj[p] = idx_j[e];
    }
}

// one wave per atom: v[i] += sum_{edges e of i} A[sorted_j] * (g[e] @ Wg.T + bg)
__global__ __launch_bounds__(256)
void agg_kernel(const int* __restrict__ off, const int* __restrict__ cnt,
                const int* __restrict__ se, const int* __restrict__ sj,
                const float* __restrict__ g,
                const float* __restrict__ Wg, const float* __restrict__ bg,
                const float* __restrict__ A, float* __restrict__ v, int N)
{
    const int t = threadIdx.x;
    const int lane = t & 63, wv = t >> 6;
    const int d0 = lane << 1;

    // this lane's two Wg rows in registers (no LDS in the hot loop)
    float wg0[20], wg1[20];
    #pragma unroll
    for (int k = 0; k < 20; ++k) {
        wg0[k] = Wg[d0 * 20 + k];
        wg1[k] = Wg[(d0 + 1) * 20 + k];
    }
    const float bg0 = bg[d0], bg1 = bg[d0 + 1];

    const int i = blockIdx.x * 4 + wv;
    if (i >= N) return;
    const int beg = off[i];
    const int num = cnt[i];

    float2 acc = *reinterpret_cast<const float2*>(v + (size_t)i * DD + d0);

    for (int p = beg; p < beg + num; ++p) {
        const int e = __builtin_amdgcn_readfirstlane(se[p]);
        const int j = __builtin_amdgcn_readfirstlane(sj[p]);

        const float4* g4 = reinterpret_cast<const float4*>(g + (size_t)e * 20);
        float gv[20];
        #pragma unroll
        for (int q = 0; q < 5; ++q) {
            const float4 pk = g4[q];   // wave-uniform address -> broadcast
            gv[q * 4 + 0] = pk.x; gv[q * 4 + 1] = pk.y;
            gv[q * 4 + 2] = pk.z; gv[q * 4 + 3] = pk.w;
        }

        float g0 = bg0, g1 = bg1;
        #pragma unroll
        for (int k = 0; k < 20; ++k) {
            g0 = fmaf(gv[k], wg0[k], g0);
            g1 = fmaf(gv[k], wg1[k], g1);
        }

        const float2 aj = *reinterpret_cast<const float2*>(A + (size_t)j * DD + d0);
        acc.x = fmaf(aj.x, g0, acc.x);
        acc.y = fmaf(aj.y, g1, acc.y);
    }

    *reinterpret_cast<float2*>(v + (size_t)i * DD + d0) = acc;
}

// fallback (ws too small): atomic edge kernel from R0
__global__ __launch_bounds__(256)
void edge_kernel(const float* __restrict__ g,
                 const int* __restrict__ idx_i,
                 const int* __restrict__ idx_j,
                 const float* __restrict__ Wg,
                 const float* __restrict__ bg,
                 const float* __restrict__ A,
                 float* __restrict__ v,
                 int E)
{
    __shared__ float Wgt[20][130];
    __shared__ float bgs[128];

    const int t = threadIdx.x;
    for (int i = t; i < 128 * 20; i += 256) {
        const int d = i / 20;
        const int k = i - d * 20;
        Wgt[k][d] = Wg[i];
    }
    if (t < 128) bgs[t] = bg[t];
    __syncthreads();

    const int lane = t & 63;
    const int d0 = lane << 1;
    const int wid = ((blockIdx.x << 8) + t) >> 6;
    const int nw  = (gridDim.x << 8) >> 6;

    for (int e = wid; e < E; e += nw) {
        const int ii = idx_i[e];
        const int jj = idx_j[e];

        const float4* g4 = reinterpret_cast<const float4*>(g + (size_t)e * 20);
        float gv[20];
        #pragma unroll
        for (int q = 0; q < 5; ++q) {
            const float4 p = g4[q];
            gv[q * 4 + 0] = p.x; gv[q * 4 + 1] = p.y;
            gv[q * 4 + 2] = p.z; gv[q * 4 + 3] = p.w;
        }

        float g0 = bgs[d0], g1 = bgs[d0 + 1];
        #pragma unroll
        for (int k = 0; k < 20; ++k) {
            const float2 w = *reinterpret_cast<const float2*>(&Wgt[k][d0]);
            g0 = fmaf(gv[k], w.x, g0);
            g1 = fmaf(gv[k], w.y, g1);
        }

        const float2 aj = *reinterpret_cast<const float2*>(A + (size_t)jj * DD + d0);
        unsafeAtomicAdd(v + (size_t)ii * DD + d0,     aj.x * g0);
        unsafeAtomicAdd(v + (size_t)ii * DD + d0 + 1, aj.y * g1);
    }
}

extern "C" void kernel_launch(void* const* d_in, const int* in_sizes, int n_in,
                              void* d_out, int out_size, void* d_ws, size_t ws_size,
                              hipStream_t stream)
{
    const float* x     = (const float*)d_in[0];
    const float* g     = (const float*)d_in[1];
    const int*   idx_i = (const int*)d_in[2];
    const int*   idx_j = (const int*)d_in[3];
    const float* u     = (const float*)d_in[5];
    const float* Wf    = (const float*)d_in[6];
    const float* bf    = (const float*)d_in[7];
    const float* Wg    = (const float*)d_in[8];
    const float* bg    = (const float*)d_in[9];
    const float* Wj    = (const float*)d_in[10];
    const float* bj    = (const float*)d_in[11];
    const float* Wi    = (const float*)d_in[12];
    const float* bi    = (const float*)d_in[13];
    const float* rw1   = (const float*)d_in[14];
    const float* rb1   = (const float*)d_in[15];
    const float* rw2   = (const float*)d_in[16];
    const float* rb2   = (const float*)d_in[17];

    const int N = in_sizes[0] / DD;   // 50000
    const int E = in_sizes[2];        // 640000
    float* out = (float*)d_out;

    // workspace layout
    float* A = (float*)d_ws;                  // [N,128]
    float* v = A + (size_t)N * DD;            // [N,128]
    float* h = A;                             // reuse A after edge pass
    int* cnt      = (int*)(v + (size_t)N * DD);
    int* off      = cnt + N;
    int* cnt2     = off + N;
    int* sorted_e = cnt2 + N;
    int* sorted_j = sorted_e + E;
    const size_t need = ((size_t)N * DD * 2) * 4 + ((size_t)N * 3 + (size_t)E * 2) * 4;

    dim3 blk(256);
    const int GB = 512;

    const int eblocks = (E + 255) / 256;
    const bool csr_ok = ws_size >= need;

    if (csr_ok) {
        hipMemsetAsync(cnt, 0, (size_t)N * 2 * sizeof(int), stream);  // cnt + off... (cnt,off adjacent; off overwritten by scan anyway)
        hipMemsetAsync(cnt2, 0, (size_t)N * sizeof(int), stream);
        hist_kernel<<<eblocks, blk, 0, stream>>>(idx_i, cnt, E);
        scan_kernel<<<1, blk, 0, stream>>>(cnt, off, N);
        scatter_kernel<<<eblocks, blk, 0, stream>>>(idx_i, idx_j, off, cnt2,
                                                    sorted_e, sorted_j, E);
    }

    // A = act(act(x) @ Wj.T + bj)
    gemm_act<1,0,0><<<GB, blk, 0, stream>>>(x, Wj, bj, nullptr, nullptr, A, N);
    // v = act(act(x) @ Wi.T + bi)
    gemm_act<1,0,0><<<GB, blk, 0, stream>>>(x, Wi, bi, nullptr, nullptr, v, N);

    if (csr_ok) {
        agg_kernel<<<(N + 3) / 4, blk, 0, stream>>>(off, cnt, sorted_e, sorted_j,
                                                    g, Wg, bg, A, v, N);
    } else {
        edge_kernel<<<2048, blk, 0, stream>>>(g, idx_i, idx_j, Wg, bg, A, v, E);
    }

    for (int l = 0; l < 3; ++l) {
        gemm_act<0,0,0><<<GB, blk, 0, stream>>>(v, rw1 + l * DD * DD, rb1 + l * DD,
                                                nullptr, nullptr, h, N);
        gemm_act<0,1,0><<<GB, blk, 0, stream>>>(h, rw2 + l * DD * DD, rb2 + l * DD,
                                                v, nullptr, v, N);
    }
    gemm_act<0,0,1><<<GB, blk, 0, stream>>>(v, Wf, bf, x, u, out, N);
}

// Round 3
// 451.456 us; speedup vs baseline: 2.1258x; 1.4233x over previous
//
#include <hip/hip_runtime.h>

#define DD 128

typedef __attribute__((ext_vector_type(8))) short short8;
typedef __attribute__((ext_vector_type(8))) unsigned short ushort8;
typedef __attribute__((ext_vector_type(4))) float floatx4;
typedef unsigned int uint32;
typedef unsigned short ushort16_t;

__device__ __forceinline__ float sp(float x) {
    return fmaxf(x, 0.0f) + __logf(1.0f + __expf(-fabsf(x)));
}

__device__ __forceinline__ unsigned short f2bf(float f) {
    union { float f; uint32 u; } c; c.f = f;
    const uint32 u = c.u;
    return (unsigned short)((u + 0x7fffu + ((u >> 16) & 1u)) >> 16);
}

__device__ __forceinline__ float bf2f(unsigned short b) {
    union { uint32 u; float f; } c; c.u = ((uint32)b) << 16;
    return c.f;
}

// stage 128x128 fp32 W into LDS as bf16, row-major, 16B-chunk XOR swizzle
__device__ __forceinline__ void stage_w(const float* __restrict__ W,
                                        unsigned short* wl, int t)
{
    #pragma unroll
    for (int i = 0; i < 8; ++i) {
        const int f8  = t + i * 256;      // chunk id 0..2047
        const int row = f8 >> 4;
        const int ch  = f8 & 15;
        const float4 a = reinterpret_cast<const float4*>(W)[2 * f8];
        const float4 b = reinterpret_cast<const float4*>(W)[2 * f8 + 1];
        ushort8 u;
        u[0] = f2bf(a.x); u[1] = f2bf(a.y); u[2] = f2bf(a.z); u[3] = f2bf(a.w);
        u[4] = f2bf(b.x); u[5] = f2bf(b.y); u[6] = f2bf(b.z); u[7] = f2bf(b.w);
        *reinterpret_cast<ushort8*>(wl + row * 128 + ((ch ^ (row & 15)) << 3)) = u;
    }
}

// per-lane A-fragments: act(X[m]) as 4 k-steps of 8 bf16
__device__ __forceinline__ void load_afrag_act(const float* __restrict__ X,
                                               int m, int q, int n, short8 af[4])
{
    const int mm = m < n ? m : n - 1;
    const float* row = X + (size_t)mm * DD + q * 8;
    #pragma unroll
    for (int kk = 0; kk < 4; ++kk) {
        const float4 a = *reinterpret_cast<const float4*>(row + kk * 32);
        const float4 b = *reinterpret_cast<const float4*>(row + kk * 32 + 4);
        ushort8 u;
        u[0] = f2bf(sp(a.x)); u[1] = f2bf(sp(a.y)); u[2] = f2bf(sp(a.z)); u[3] = f2bf(sp(a.w));
        u[4] = f2bf(sp(b.x)); u[5] = f2bf(sp(b.y)); u[6] = f2bf(sp(b.z)); u[7] = f2bf(sp(b.w));
        af[kk] = __builtin_bit_cast(short8, u);
    }
}

// 16x128 per-wave GEMM: acc[nt] += A(16x32,kk) * W^T chunks
__device__ __forceinline__ void mfma_gemm(const unsigned short* wl,
                                          const short8 af[4],
                                          int cl, int q, floatx4 acc[8])
{
    #pragma unroll
    for (int nt = 0; nt < 8; ++nt) {
        const int nrow = nt * 16 + cl;     // nrow & 15 == cl
        #pragma unroll
        for (int kk = 0; kk < 4; ++kk) {
            const int chs = (kk * 4 + q) ^ cl;
            const short8 bfr = *reinterpret_cast<const short8*>(wl + nrow * 128 + (chs << 3));
            acc[nt] = __builtin_amdgcn_mfma_f32_16x16x32_bf16(af[kk], bfr, acc[nt], 0, 0, 0);
        }
    }
}

// A = act(act(x)@Wj.T+bj) [bf16], v = act(act(x)@Wi.T+bi) [f32]
__global__ __launch_bounds__(256, 2)
void dual_gemm(const float* __restrict__ x,
               const float* __restrict__ Wj, const float* __restrict__ bj,
               const float* __restrict__ Wi, const float* __restrict__ bi,
               unsigned short* __restrict__ Aout, float* __restrict__ vout, int n)
{
    __shared__ __align__(16) unsigned short wl[128 * 128];
    const int t = threadIdx.x;
    const int lane = t & 63, wv = t >> 6;
    const int cl = lane & 15, q = lane >> 4;
    const int m0 = blockIdx.x * 64 + wv * 16;

    short8 af[4];
    load_afrag_act(x, m0 + cl, q, n, af);

    stage_w(Wj, wl, t);
    __syncthreads();

    floatx4 acc[8];
    #pragma unroll
    for (int nt = 0; nt < 8; ++nt) acc[nt] = (floatx4){0.f, 0.f, 0.f, 0.f};
    mfma_gemm(wl, af, cl, q, acc);

    #pragma unroll
    for (int nt = 0; nt < 8; ++nt) {
        const int col = nt * 16 + cl;
        const float bb = bj[col];
        #pragma unroll
        for (int r = 0; r < 4; ++r) {
            const int row = m0 + q * 4 + r;
            if (row < n) Aout[(size_t)row * DD + col] = f2bf(sp(acc[nt][r] + bb));
        }
    }

    __syncthreads();
    stage_w(Wi, wl, t);
    __syncthreads();

    #pragma unroll
    for (int nt = 0; nt < 8; ++nt) acc[nt] = (floatx4){0.f, 0.f, 0.f, 0.f};
    mfma_gemm(wl, af, cl, q, acc);

    #pragma unroll
    for (int nt = 0; nt < 8; ++nt) {
        const int col = nt * 16 + cl;
        const float bb = bi[col];
        #pragma unroll
        for (int r = 0; r < 4; ++r) {
            const int row = m0 + q * 4 + r;
            if (row < n) vout[(size_t)row * DD + col] = sp(acc[nt][r] + bb);
        }
    }
}

// fused residual layer: v = act(act(v)@W1.T+b1... ) chain, in place
__global__ __launch_bounds__(256, 2)
void res_layer(float* __restrict__ v,
               const float* __restrict__ W1, const float* __restrict__ b1,
               const float* __restrict__ W2, const float* __restrict__ b2, int n)
{
    __shared__ __align__(16) unsigned short wl[128 * 128];
    __shared__ __align__(16) unsigned short hl[64 * 128];
    const int t = threadIdx.x;
    const int lane = t & 63, wv = t >> 6;
    const int cl = lane & 15, q = lane >> 4;
    const int m0 = blockIdx.x * 64 + wv * 16;

    short8 af[4];
    load_afrag_act(v, m0 + cl, q, n, af);

    stage_w(W1, wl, t);
    __syncthreads();

    floatx4 acc[8];
    #pragma unroll
    for (int nt = 0; nt < 8; ++nt) acc[nt] = (floatx4){0.f, 0.f, 0.f, 0.f};
    mfma_gemm(wl, af, cl, q, acc);

    // h-tile = act(acc + b1) -> LDS bf16 (swizzled row-major [64][128])
    #pragma unroll
    for (int nt = 0; nt < 8; ++nt) {
        const int col = nt * 16 + cl;
        const int ch = col >> 3;
        const float bb = b1[col];
        #pragma unroll
        for (int r = 0; r < 4; ++r) {
            const int mloc = wv * 16 + q * 4 + r;
            hl[mloc * 128 + ((ch ^ (mloc & 15)) << 3) + (col & 7)] =
                f2bf(sp(acc[nt][r] + bb));
        }
    }
    __syncthreads();           // h writes + W1 reads complete
    stage_w(W2, wl, t);
    __syncthreads();

    // second GEMM: A-frags from h-tile
    short8 af2[4];
    const int mloc2 = wv * 16 + cl;     // mloc2 & 15 == cl
    #pragma unroll
    for (int kk = 0; kk < 4; ++kk) {
        const int chs = (kk * 4 + q) ^ cl;
        af2[kk] = *reinterpret_cast<const short8*>(hl + mloc2 * 128 + (chs << 3));
    }

    #pragma unroll
    for (int nt = 0; nt < 8; ++nt) acc[nt] = (floatx4){0.f, 0.f, 0.f, 0.f};
    mfma_gemm(wl, af2, cl, q, acc);

    #pragma unroll
    for (int nt = 0; nt < 8; ++nt) {
        const int col = nt * 16 + cl;
        const float bb = b2[col];
        #pragma unroll
        for (int r = 0; r < 4; ++r) {
            const int row = m0 + q * 4 + r;
            if (row < n) {
                float* p = v + (size_t)row * DD + col;
                *p = acc[nt][r] + bb + *p;
            }
        }
    }
}

// out = u*x + act(v)@Wf.T + bf
__global__ __launch_bounds__(256, 2)
void final_gemm(const float* __restrict__ v, const float* __restrict__ x,
                const float* __restrict__ Wf, const float* __restrict__ bf,
                const float* __restrict__ u, float* __restrict__ out, int n)
{
    __shared__ __align__(16) unsigned short wl[128 * 128];
    const int t = threadIdx.x;
    const int lane = t & 63, wv = t >> 6;
    const int cl = lane & 15, q = lane >> 4;
    const int m0 = blockIdx.x * 64 + wv * 16;

    short8 af[4];
    load_afrag_act(v, m0 + cl, q, n, af);

    stage_w(Wf, wl, t);
    __syncthreads();

    floatx4 acc[8];
    #pragma unroll
    for (int nt = 0; nt < 8; ++nt) acc[nt] = (floatx4){0.f, 0.f, 0.f, 0.f};
    mfma_gemm(wl, af, cl, q, acc);

    #pragma unroll
    for (int nt = 0; nt < 8; ++nt) {
        const int col = nt * 16 + cl;
        const float bb = bf[col];
        const float uu = u[col];
        #pragma unroll
        for (int r = 0; r < 4; ++r) {
            const int row = m0 + q * 4 + r;
            if (row < n)
                out[(size_t)row * DD + col] =
                    acc[nt][r] + bb + uu * x[(size_t)row * DD + col];
        }
    }
}

// ---------- CSR build ----------

__global__ __launch_bounds__(256)
void hist_kernel(const int* __restrict__ idx_i, int* __restrict__ cnt, int E)
{
    const int e = blockIdx.x * 256 + threadIdx.x;
    if (e < E) atomicAdd(&cnt[idx_i[e]], 1);
}

__global__ __launch_bounds__(256)
void scan_kernel(const int* __restrict__ cnt, int* __restrict__ off, int n)
{
    __shared__ int wsum[4];
    __shared__ int carry_s;
    const int t = threadIdx.x;
    const int lane = t & 63, wv = t >> 6;
    if (t == 0) carry_s = 0;
    __syncthreads();
    for (int base = 0; base < n; base += 1024) {
        const int i0 = base + t * 4;
        const int v0 = (i0 + 0 < n) ? cnt[i0 + 0] : 0;
        const int v1 = (i0 + 1 < n) ? cnt[i0 + 1] : 0;
        const int v2 = (i0 + 2 < n) ? cnt[i0 + 2] : 0;
        const int v3 = (i0 + 3 < n) ? cnt[i0 + 3] : 0;
        const int s = v0 + v1 + v2 + v3;
        int incl = s;
        #pragma unroll
        for (int d = 1; d < 64; d <<= 1) {
            const int y = __shfl_up(incl, d, 64);
            if (lane >= d) incl += y;
        }
        if (lane == 63) wsum[wv] = incl;
        __syncthreads();
        int woff = 0;
        #pragma unroll
        for (int w = 0; w < 4; ++w) if (w < wv) woff += wsum[w];
        const int excl = carry_s + woff + incl - s;
        if (i0 + 0 < n) off[i0 + 0] = excl;
        if (i0 + 1 < n) off[i0 + 1] = excl + v0;
        if (i0 + 2 < n) off[i0 + 2] = excl + v0 + v1;
        if (i0 + 3 < n) off[i0 + 3] = excl + v0 + v1 + v2;
        __syncthreads();
        if (t == 255) carry_s += woff + incl;
        __syncthreads();
    }
}

__global__ __launch_bounds__(256)
void scatter_kernel(const int* __restrict__ idx_i, const int* __restrict__ idx_j,
                    const int* __restrict__ off, int* __restrict__ cnt2,
                    int2* __restrict__ spair, int E)
{
    const int e = blockIdx.x * 256 + threadIdx.x;
    if (e < E) {
        const int i = idx_i[e];
        const int p = off[i] + atomicAdd(&cnt2[i], 1);
        spair[p] = make_int2(e, idx_j[e]);
    }
}

// one wave per atom, software-pipelined gather
__global__ __launch_bounds__(256, 2)
void agg_kernel(const int* __restrict__ off, const int* __restrict__ cnt,
                const int2* __restrict__ spair,
                const float* __restrict__ g,
                const float* __restrict__ Wg, const float* __restrict__ bg,
                const unsigned short* __restrict__ A, float* __restrict__ v, int N)
{
    const int t = threadIdx.x;
    const int lane = t & 63, wv = t >> 6;
    const int d0 = lane << 1;

    float wg0[20], wg1[20];
    #pragma unroll
    for (int k = 0; k < 20; ++k) {
        wg0[k] = Wg[d0 * 20 + k];
        wg1[k] = Wg[(d0 + 1) * 20 + k];
    }
    const float bg0 = bg[d0], bg1 = bg[d0 + 1];

    const int i = blockIdx.x * 4 + wv;
    if (i >= N) return;
    const int beg = off[i], num = cnt[i], end = beg + num;

    float2 acc = *reinterpret_cast<const float2*>(v + (size_t)i * DD + d0);

    if (num > 0) {
        int2 pr = spair[beg];
        int e_c = __builtin_amdgcn_readfirstlane(pr.x);
        int j_c = __builtin_amdgcn_readfirstlane(pr.y);
        float gs[20];
        {
            const float4* g4 = reinterpret_cast<const float4*>(g + (size_t)e_c * 20);
            #pragma unroll
            for (int qq = 0; qq < 5; ++qq) {
                const float4 pk = g4[qq];
                gs[4 * qq + 0] = pk.x; gs[4 * qq + 1] = pk.y;
                gs[4 * qq + 2] = pk.z; gs[4 * qq + 3] = pk.w;
            }
        }
        uint32 a2 = *reinterpret_cast<const uint32*>(A + (size_t)j_c * DD + d0);
        int e_n = e_c, j_n = j_c;
        if (num > 1) {
            int2 pr2 = spair[beg + 1];
            e_n = __builtin_amdgcn_readfirstlane(pr2.x);
            j_n = __builtin_amdgcn_readfirstlane(pr2.y);
        }

        for (int p = beg; p < end; ++p) {
            uint32 a2_n = 0;
            if (p + 1 < end)
                a2_n = *reinterpret_cast<const uint32*>(A + (size_t)j_n * DD + d0);
            int e_nn = e_n, j_nn = j_n;
            if (p + 2 < end) {
                int2 pr3 = spair[p + 2];
                e_nn = __builtin_amdgcn_readfirstlane(pr3.x);
                j_nn = __builtin_amdgcn_readfirstlane(pr3.y);
            }
            float g0 = bg0, g1 = bg1;
            #pragma unroll
            for (int k = 0; k < 20; ++k) {
                g0 = fmaf(gs[k], wg0[k], g0);
                g1 = fmaf(gs[k], wg1[k], g1);
            }
            union { uint32 u; float f; } cx, cy;
            cx.u = a2 << 16;
            cy.u = a2 & 0xffff0000u;
            acc.x = fmaf(cx.f, g0, acc.x);
            acc.y = fmaf(cy.f, g1, acc.y);
            if (p + 1 < end) {
                const float4* g4 = reinterpret_cast<const float4*>(g + (size_t)e_n * 20);
                #pragma unroll
                for (int qq = 0; qq < 5; ++qq) {
                    const float4 pk = g4[qq];
                    gs[4 * qq + 0] = pk.x; gs[4 * qq + 1] = pk.y;
                    gs[4 * qq + 2] = pk.z; gs[4 * qq + 3] = pk.w;
                }
            }
            a2 = a2_n; e_n = e_nn; j_n = j_nn;
        }
    }
    *reinterpret_cast<float2*>(v + (size_t)i * DD + d0) = acc;
}

extern "C" void kernel_launch(void* const* d_in, const int* in_sizes, int n_in,
                              void* d_out, int out_size, void* d_ws, size_t ws_size,
                              hipStream_t stream)
{
    const float* x     = (const float*)d_in[0];
    const float* g     = (const float*)d_in[1];
    const int*   idx_i = (const int*)d_in[2];
    const int*   idx_j = (const int*)d_in[3];
    const float* u     = (const float*)d_in[5];
    const float* Wf    = (const float*)d_in[6];
    const float* bf    = (const float*)d_in[7];
    const float* Wg    = (const float*)d_in[8];
    const float* bg    = (const float*)d_in[9];
    const float* Wj    = (const float*)d_in[10];
    const float* bj    = (const float*)d_in[11];
    const float* Wi    = (const float*)d_in[12];
    const float* bi    = (const float*)d_in[13];
    const float* rw1   = (const float*)d_in[14];
    const float* rb1   = (const float*)d_in[15];
    const float* rw2   = (const float*)d_in[16];
    const float* rb2   = (const float*)d_in[17];

    const int N = in_sizes[0] / DD;   // 50000
    const int E = in_sizes[2];        // 640000
    float* out = (float*)d_out;

    // workspace layout
    float*          v     = (float*)d_ws;                    // [N,128] f32
    unsigned short* A     = (unsigned short*)(v + (size_t)N * DD);  // [N,128] bf16
    int*            cnt   = (int*)(A + (size_t)N * DD);
    int*            off   = cnt + N;
    int*            cnt2  = off + N;
    int2*           spair = (int2*)(cnt2 + N);

    dim3 blk(256);
    const int tiles   = (N + 63) / 64;
    const int eblocks = (E + 255) / 256;

    hipMemsetAsync(cnt, 0, (size_t)N * sizeof(int), stream);
    hipMemsetAsync(cnt2, 0, (size_t)N * sizeof(int), stream);
    hist_kernel<<<eblocks, blk, 0, stream>>>(idx_i, cnt, E);
    scan_kernel<<<1, blk, 0, stream>>>(cnt, off, N);
    scatter_kernel<<<eblocks, blk, 0, stream>>>(idx_i, idx_j, off, cnt2, spair, E);

    dual_gemm<<<tiles, blk, 0, stream>>>(x, Wj, bj, Wi, bi, A, v, N);

    agg_kernel<<<(N + 3) / 4, blk, 0, stream>>>(off, cnt, spair, g, Wg, bg, A, v, N);

    for (int l = 0; l < 3; ++l) {
        res_layer<<<tiles, blk, 0, stream>>>(v, rw1 + (size_t)l * DD * DD, rb1 + (size_t)l * DD,
                                             rw2 + (size_t)l * DD * DD, rb2 + (size_t)l * DD, N);
    }
    final_gemm<<<tiles, blk, 0, stream>>>(v, x, Wf, bf, u, out, N);
}

// Round 4
// 309.730 us; speedup vs baseline: 3.0985x; 1.4576x over previous
//
#include <hip/hip_runtime.h>

#define DD 128

typedef __attribute__((ext_vector_type(8))) short short8;
typedef __attribute__((ext_vector_type(8))) unsigned short ushort8;
typedef __attribute__((ext_vector_type(4))) float floatx4;
typedef unsigned int uint32;

__device__ __forceinline__ float sp(float x) {
    return fmaxf(x, 0.0f) + __logf(1.0f + __expf(-fabsf(x)));
}

__device__ __forceinline__ unsigned short f2bf(float f) {
    union { float f; uint32 u; } c; c.f = f;
    const uint32 u = c.u;
    return (unsigned short)((u + 0x7fffu + ((u >> 16) & 1u)) >> 16);
}

// ---------- weight preconvert: f32 [128][128] -> bf16, 16B-chunk XOR swizzled ----------
__global__ __launch_bounds__(256)
void convert_w(const float* __restrict__ Wj, const float* __restrict__ Wi,
               const float* __restrict__ rw1, const float* __restrict__ rw2,
               const float* __restrict__ Wf, unsigned short* __restrict__ out)
{
    const int gid = blockIdx.x * 256 + threadIdx.x;   // 8-float chunk id
    if (gid >= 9 * 2048) return;
    const int mat = gid >> 11;
    const int f8  = gid & 2047;
    const float* src;
    if      (mat == 0) src = Wj;
    else if (mat == 1) src = Wi;
    else if (mat <= 4) src = rw1 + (size_t)(mat - 2) * 16384;
    else if (mat <= 7) src = rw2 + (size_t)(mat - 5) * 16384;
    else               src = Wf;
    const int row = f8 >> 4;
    const int ch  = f8 & 15;
    const float4 a = reinterpret_cast<const float4*>(src)[2 * f8];
    const float4 b = reinterpret_cast<const float4*>(src)[2 * f8 + 1];
    ushort8 u8;
    u8[0] = f2bf(a.x); u8[1] = f2bf(a.y); u8[2] = f2bf(a.z); u8[3] = f2bf(a.w);
    u8[4] = f2bf(b.x); u8[5] = f2bf(b.y); u8[6] = f2bf(b.z); u8[7] = f2bf(b.w);
    *reinterpret_cast<ushort8*>(out + (size_t)mat * 16384 + row * 128 +
                                ((ch ^ (row & 15)) << 3)) = u8;
}

// stage preswizzled bf16 weight: pure linear 32KB copy
__device__ __forceinline__ void stage_wb(const unsigned short* __restrict__ Wb,
                                         unsigned short* wl, int t)
{
    #pragma unroll
    for (int i = 0; i < 8; ++i) {
        const int c = t + i * 256;
        *reinterpret_cast<ushort8*>(wl + c * 8) =
            *reinterpret_cast<const ushort8*>(Wb + c * 8);
    }
}

// per-lane A-fragments from global f32 row: act -> bf16, 4 k-steps of 8
__device__ __forceinline__ void load_afrag_act(const float* __restrict__ X,
                                               int m, int q, int n, short8 af[4])
{
    const int mm = m < n ? m : n - 1;
    const float* row = X + (size_t)mm * DD + q * 8;
    #pragma unroll
    for (int kk = 0; kk < 4; ++kk) {
        const float4 a = *reinterpret_cast<const float4*>(row + kk * 32);
        const float4 b = *reinterpret_cast<const float4*>(row + kk * 32 + 4);
        ushort8 u;
        u[0] = f2bf(sp(a.x)); u[1] = f2bf(sp(a.y)); u[2] = f2bf(sp(a.z)); u[3] = f2bf(sp(a.w));
        u[4] = f2bf(sp(b.x)); u[5] = f2bf(sp(b.y)); u[6] = f2bf(sp(b.z)); u[7] = f2bf(sp(b.w));
        af[kk] = __builtin_bit_cast(short8, u);
    }
}

// 16x128 per-wave GEMM on swizzled LDS weight tile
__device__ __forceinline__ void mfma_gemm(const unsigned short* wl,
                                          const short8 af[4],
                                          int cl, int q, floatx4 acc[8])
{
    #pragma unroll
    for (int nt = 0; nt < 8; ++nt) {
        const int nrow = nt * 16 + cl;
        #pragma unroll
        for (int kk = 0; kk < 4; ++kk) {
            const int chs = (kk * 4 + q) ^ cl;
            const short8 bfr = *reinterpret_cast<const short8*>(wl + nrow * 128 + (chs << 3));
            acc[nt] = __builtin_amdgcn_mfma_f32_16x16x32_bf16(af[kk], bfr, acc[nt], 0, 0, 0);
        }
    }
}

// A = act(act(x)@Wj.T+bj) [bf16], v = act(act(x)@Wi.T+bi) [f32]
__global__ __launch_bounds__(256, 4)
void dual_gemm(const float* __restrict__ x,
               const unsigned short* __restrict__ Wb,
               const float* __restrict__ bj, const float* __restrict__ bi,
               unsigned short* __restrict__ Aout, float* __restrict__ vout, int n)
{
    __shared__ __align__(16) unsigned short wl[128 * 128];
    const int t = threadIdx.x;
    const int lane = t & 63, wv = t >> 6;
    const int cl = lane & 15, q = lane >> 4;
    const int m0 = blockIdx.x * 64 + wv * 16;

    short8 af[4];
    load_afrag_act(x, m0 + cl, q, n, af);

    stage_wb(Wb, wl, t);
    __syncthreads();

    floatx4 acc[8];
    #pragma unroll
    for (int nt = 0; nt < 8; ++nt) acc[nt] = (floatx4){0.f, 0.f, 0.f, 0.f};
    mfma_gemm(wl, af, cl, q, acc);

    #pragma unroll
    for (int nt = 0; nt < 8; ++nt) {
        const int col = nt * 16 + cl;
        const float bb = bj[col];
        #pragma unroll
        for (int r = 0; r < 4; ++r) {
            const int row = m0 + q * 4 + r;
            if (row < n) Aout[(size_t)row * DD + col] = f2bf(sp(acc[nt][r] + bb));
        }
    }

    __syncthreads();
    stage_wb(Wb + 16384, wl, t);
    __syncthreads();

    #pragma unroll
    for (int nt = 0; nt < 8; ++nt) acc[nt] = (floatx4){0.f, 0.f, 0.f, 0.f};
    mfma_gemm(wl, af, cl, q, acc);

    #pragma unroll
    for (int nt = 0; nt < 8; ++nt) {
        const int col = nt * 16 + cl;
        const float bb = bi[col];
        #pragma unroll
        for (int r = 0; r < 4; ++r) {
            const int row = m0 + q * 4 + r;
            if (row < n) vout[(size_t)row * DD + col] = sp(acc[nt][r] + bb);
        }
    }
}

// fused tail: 3 residual layers + final output, v kept in registers
__global__ __launch_bounds__(256, 2)
void tail_kernel(const float* __restrict__ vin, const float* __restrict__ x,
                 const unsigned short* __restrict__ Wb,   // mats 2..8 used
                 const float* __restrict__ rb1, const float* __restrict__ rb2,
                 const float* __restrict__ bf, const float* __restrict__ u,
                 float* __restrict__ out, int n)
{
    __shared__ __align__(16) unsigned short wl[128 * 128];  // 32 KB weight tile
    __shared__ __align__(16) unsigned short hl[64 * 128];   // 16 KB h tile (bf16)
    __shared__ __align__(16) float vt[64 * 128];             // 32 KB v/x tile (f32)
    const int t = threadIdx.x;
    const int lane = t & 63, wv = t >> 6;
    const int cl = lane & 15, q = lane >> 4;
    const int mb = blockIdx.x * 64;
    const int m0 = mb + wv * 16;
    (void)m0;

    // stage v tile (coalesced, 16B-chunk XOR swizzle) + first weight
    #pragma unroll
    for (int i = 0; i < 8; ++i) {
        const int c = t + i * 256;            // float4 chunk 0..2047
        const int row = c >> 5;
        const int chv = c & 31;
        float4 val = make_float4(0.f, 0.f, 0.f, 0.f);
        if (mb + row < n) val = reinterpret_cast<const float4*>(vin)[(size_t)mb * 32 + c];
        *reinterpret_cast<float4*>(vt + row * 128 + ((chv ^ (row & 15)) << 2)) = val;
    }
    stage_wb(Wb + 2 * 16384, wl, t);
    __syncthreads();

    // v accumulator in D-layout registers
    floatx4 vac[8];
    #pragma unroll
    for (int nt = 0; nt < 8; ++nt) {
        #pragma unroll
        for (int r = 0; r < 4; ++r) {
            const int rl = wv * 16 + q * 4 + r;
            const int col = nt * 16 + cl;
            const int chv = col >> 2;
            vac[nt][r] = vt[rl * 128 + ((chv ^ (rl & 15)) << 2) + (col & 3)];
        }
    }

    // layer-0 A-fragments straight from vt
    short8 af[4];
    {
        const int rl = wv * 16 + cl;
        #pragma unroll
        for (int kk = 0; kk < 4; ++kk) {
            const int c0 = q * 2 + kk * 8;
            const floatx4 A0 = *reinterpret_cast<const floatx4*>(vt + rl * 128 + (((c0    ) ^ cl) << 2));
            const floatx4 A1 = *reinterpret_cast<const floatx4*>(vt + rl * 128 + (((c0 + 1) ^ cl) << 2));
            ushort8 u8;
            u8[0] = f2bf(sp(A0[0])); u8[1] = f2bf(sp(A0[1])); u8[2] = f2bf(sp(A0[2])); u8[3] = f2bf(sp(A0[3]));
            u8[4] = f2bf(sp(A1[0])); u8[5] = f2bf(sp(A1[1])); u8[6] = f2bf(sp(A1[2])); u8[7] = f2bf(sp(A1[3]));
            af[kk] = __builtin_bit_cast(short8, u8);
        }
    }

    const int ml2 = wv * 16 + cl;

    for (int l = 0; l < 3; ++l) {
        if (l > 0) {
            // af = act(vac) via per-wave hl region (same-wave LDS, no barrier needed)
            #pragma unroll
            for (int nt = 0; nt < 8; ++nt) {
                const int col = nt * 16 + cl;
                const int ch = col >> 3;
                #pragma unroll
                for (int r = 0; r < 4; ++r) {
                    const int ml = wv * 16 + q * 4 + r;
                    hl[ml * 128 + ((ch ^ (ml & 15)) << 3) + (col & 7)] = f2bf(sp(vac[nt][r]));
                }
            }
            #pragma unroll
            for (int kk = 0; kk < 4; ++kk)
                af[kk] = *reinterpret_cast<const short8*>(hl + ml2 * 128 + (((kk * 4 + q) ^ cl) << 3));
            __syncthreads();                       // prev layer's wl reads done
            stage_wb(Wb + (size_t)(2 + l) * 16384, wl, t);
            __syncthreads();
        }

        floatx4 acc[8];
        #pragma unroll
        for (int nt = 0; nt < 8; ++nt) acc[nt] = (floatx4){0.f, 0.f, 0.f, 0.f};
        mfma_gemm(wl, af, cl, q, acc);

        // h2 = act(h + b1) -> hl, then second A-fragments
        const float* b1 = rb1 + (size_t)l * DD;
        #pragma unroll
        for (int nt = 0; nt < 8; ++nt) {
            const int col = nt * 16 + cl;
            const int ch = col >> 3;
            const float bb = b1[col];
            #pragma unroll
            for (int r = 0; r < 4; ++r) {
                const int ml = wv * 16 + q * 4 + r;
                hl[ml * 128 + ((ch ^ (ml & 15)) << 3) + (col & 7)] = f2bf(sp(acc[nt][r] + bb));
            }
        }
        short8 af2[4];
        #pragma unroll
        for (int kk = 0; kk < 4; ++kk)
            af2[kk] = *reinterpret_cast<const short8*>(hl + ml2 * 128 + (((kk * 4 + q) ^ cl) << 3));

        __syncthreads();
        stage_wb(Wb + (size_t)(5 + l) * 16384, wl, t);
        __syncthreads();

        #pragma unroll
        for (int nt = 0; nt < 8; ++nt) acc[nt] = (floatx4){0.f, 0.f, 0.f, 0.f};
        mfma_gemm(wl, af2, cl, q, acc);

        const float* b2 = rb2 + (size_t)l * DD;
        #pragma unroll
        for (int nt = 0; nt < 8; ++nt) {
            const float bb = b2[nt * 16 + cl];
            #pragma unroll
            for (int r = 0; r < 4; ++r) vac[nt][r] += acc[nt][r] + bb;
        }
    }

    // final: out = u*x + act(v)@Wf.T + bf
    __syncthreads();
    stage_wb(Wb + (size_t)8 * 16384, wl, t);
    #pragma unroll
    for (int i = 0; i < 8; ++i) {
        const int c = t + i * 256;
        const int row = c >> 5;
        const int chv = c & 31;
        float4 val = make_float4(0.f, 0.f, 0.f, 0.f);
        if (mb + row < n) val = reinterpret_cast<const float4*>(x)[(size_t)mb * 32 + c];
        *reinterpret_cast<float4*>(vt + row * 128 + ((chv ^ (row & 15)) << 2)) = val;
    }
    __syncthreads();

    #pragma unroll
    for (int nt = 0; nt < 8; ++nt) {
        const int col = nt * 16 + cl;
        const int ch = col >> 3;
        #pragma unroll
        for (int r = 0; r < 4; ++r) {
            const int ml = wv * 16 + q * 4 + r;
            hl[ml * 128 + ((ch ^ (ml & 15)) << 3) + (col & 7)] = f2bf(sp(vac[nt][r]));
        }
    }
    short8 aff[4];
    #pragma unroll
    for (int kk = 0; kk < 4; ++kk)
        aff[kk] = *reinterpret_cast<const short8*>(hl + ml2 * 128 + (((kk * 4 + q) ^ cl) << 3));

    floatx4 acc[8];
    #pragma unroll
    for (int nt = 0; nt < 8; ++nt) acc[nt] = (floatx4){0.f, 0.f, 0.f, 0.f};
    mfma_gemm(wl, aff, cl, q, acc);

    #pragma unroll
    for (int nt = 0; nt < 8; ++nt) {
        const int col = nt * 16 + cl;
        const float bb = bf[col];
        const float uu = u[col];
        const int chv = col >> 2;
        #pragma unroll
        for (int r = 0; r < 4; ++r) {
            const int rl = wv * 16 + q * 4 + r;
            const int row = mb + rl;
            if (row < n) {
                const float xv = vt[rl * 128 + ((chv ^ (rl & 15)) << 2) + (col & 3)];
                out[(size_t)row * DD + col] = acc[nt][r] + bb + uu * xv;
            }
        }
    }
}

// ---------- CSR build ----------

__global__ __launch_bounds__(256)
void hist_kernel(const int* __restrict__ idx_i, int* __restrict__ cnt, int E)
{
    const int e = blockIdx.x * 256 + threadIdx.x;
    if (e < E) atomicAdd(&cnt[idx_i[e]], 1);
}

__global__ __launch_bounds__(256)
void scan_kernel(const int* __restrict__ cnt, int* __restrict__ off, int n)
{
    __shared__ int wsum[4];
    __shared__ int carry_s;
    const int t = threadIdx.x;
    const int lane = t & 63, wv = t >> 6;
    if (t == 0) carry_s = 0;
    __syncthreads();
    for (int base = 0; base < n; base += 1024) {
        const int i0 = base + t * 4;
        const int v0 = (i0 + 0 < n) ? cnt[i0 + 0] : 0;
        const int v1 = (i0 + 1 < n) ? cnt[i0 + 1] : 0;
        const int v2 = (i0 + 2 < n) ? cnt[i0 + 2] : 0;
        const int v3 = (i0 + 3 < n) ? cnt[i0 + 3] : 0;
        const int s = v0 + v1 + v2 + v3;
        int incl = s;
        #pragma unroll
        for (int d = 1; d < 64; d <<= 1) {
            const int y = __shfl_up(incl, d, 64);
            if (lane >= d) incl += y;
        }
        if (lane == 63) wsum[wv] = incl;
        __syncthreads();
        int woff = 0;
        #pragma unroll
        for (int w = 0; w < 4; ++w) if (w < wv) woff += wsum[w];
        const int excl = carry_s + woff + incl - s;
        if (i0 + 0 < n) off[i0 + 0] = excl;
        if (i0 + 1 < n) off[i0 + 1] = excl + v0;
        if (i0 + 2 < n) off[i0 + 2] = excl + v0 + v1;
        if (i0 + 3 < n) off[i0 + 3] = excl + v0 + v1 + v2;
        __syncthreads();
        if (t == 255) carry_s += woff + incl;
        __syncthreads();
    }
}

__global__ __launch_bounds__(256)
void scatter_kernel(const int* __restrict__ idx_i, const int* __restrict__ idx_j,
                    const int* __restrict__ off, int* __restrict__ cnt2,
                    int2* __restrict__ spair, int E)
{
    const int e = blockIdx.x * 256 + threadIdx.x;
    if (e < E) {
        const int i = idx_i[e];
        const int p = off[i] + atomicAdd(&cnt2[i], 1);
        spair[p] = make_int2(e, idx_j[e]);
    }
}

// one wave per atom, clean 2-edge unroll
__global__ __launch_bounds__(256, 4)
void agg_kernel(const int* __restrict__ off, const int* __restrict__ cnt,
                const int2* __restrict__ spair,
                const float* __restrict__ g,
                const float* __restrict__ Wg, const float* __restrict__ bg,
                const unsigned short* __restrict__ A, float* __restrict__ v, int N)
{
    const int t = threadIdx.x;
    const int lane = t & 63, wv = t >> 6;
    const int d0 = lane << 1;

    float2 wg01[20];
    #pragma unroll
    for (int k = 0; k < 20; ++k) {
        wg01[k].x = Wg[d0 * 20 + k];
        wg01[k].y = Wg[(d0 + 1) * 20 + k];
    }
    const float bg0 = bg[d0], bg1 = bg[d0 + 1];

    const int i = blockIdx.x * 4 + wv;
    if (i >= N) return;
    const int beg = off[i], num = cnt[i], end = beg + num;

    float2 acc = *reinterpret_cast<const float2*>(v + (size_t)i * DD + d0);

    int p = beg;
    for (; p + 2 <= end; p += 2) {
        const int2 pr0 = spair[p];
        const int2 pr1 = spair[p + 1];
        const int e0 = __builtin_amdgcn_readfirstlane(pr0.x);
        const int j0 = __builtin_amdgcn_readfirstlane(pr0.y);
        const int e1 = __builtin_amdgcn_readfirstlane(pr1.x);
        const int j1 = __builtin_amdgcn_readfirstlane(pr1.y);
        const uint32 a0 = *reinterpret_cast<const uint32*>(A + (size_t)j0 * DD + d0);
        const uint32 a1 = *reinterpret_cast<const uint32*>(A + (size_t)j1 * DD + d0);
        const float4* g0p = reinterpret_cast<const float4*>(g + (size_t)e0 * 20);
        const float4* g1p = reinterpret_cast<const float4*>(g + (size_t)e1 * 20);
        float2 t0 = make_float2(bg0, bg1), t1 = make_float2(bg0, bg1);
        #pragma unroll
        for (int qq = 0; qq < 5; ++qq) {
            const float4 p0 = g0p[qq];
            const float4 p1 = g1p[qq];
            t0.x = fmaf(p0.x, wg01[qq*4+0].x, t0.x); t0.y = fmaf(p0.x, wg01[qq*4+0].y, t0.y);
            t0.x = fmaf(p0.y, wg01[qq*4+1].x, t0.x); t0.y = fmaf(p0.y, wg01[qq*4+1].y, t0.y);
            t0.x = fmaf(p0.z, wg01[qq*4+2].x, t0.x); t0.y = fmaf(p0.z, wg01[qq*4+2].y, t0.y);
            t0.x = fmaf(p0.w, wg01[qq*4+3].x, t0.x); t0.y = fmaf(p0.w, wg01[qq*4+3].y, t0.y);
            t1.x = fmaf(p1.x, wg01[qq*4+0].x, t1.x); t1.y = fmaf(p1.x, wg01[qq*4+0].y, t1.y);
            t1.x = fmaf(p1.y, wg01[qq*4+1].x, t1.x); t1.y = fmaf(p1.y, wg01[qq*4+1].y, t1.y);
            t1.x = fmaf(p1.z, wg01[qq*4+2].x, t1.x); t1.y = fmaf(p1.z, wg01[qq*4+2].y, t1.y);
            t1.x = fmaf(p1.w, wg01[qq*4+3].x, t1.x); t1.y = fmaf(p1.w, wg01[qq*4+3].y, t1.y);
        }
        union { uint32 u; float f; } c0x, c0y, c1x, c1y;
        c0x.u = a0 << 16; c0y.u = a0 & 0xffff0000u;
        c1x.u = a1 << 16; c1y.u = a1 & 0xffff0000u;
        acc.x = fmaf(c0x.f, t0.x, acc.x); acc.y = fmaf(c0y.f, t0.y, acc.y);
        acc.x = fmaf(c1x.f, t1.x, acc.x); acc.y = fmaf(c1y.f, t1.y, acc.y);
    }
    if (p < end) {
        const int2 pr0 = spair[p];
        const int e0 = __builtin_amdgcn_readfirstlane(pr0.x);
        const int j0 = __builtin_amdgcn_readfirstlane(pr0.y);
        const uint32 a0 = *reinterpret_cast<const uint32*>(A + (size_t)j0 * DD + d0);
        const float4* g0p = reinterpret_cast<const float4*>(g + (size_t)e0 * 20);
        float2 t0 = make_float2(bg0, bg1);
        #pragma unroll
        for (int qq = 0; qq < 5; ++qq) {
            const float4 p0 = g0p[qq];
            t0.x = fmaf(p0.x, wg01[qq*4+0].x, t0.x); t0.y = fmaf(p0.x, wg01[qq*4+0].y, t0.y);
            t0.x = fmaf(p0.y, wg01[qq*4+1].x, t0.x); t0.y = fmaf(p0.y, wg01[qq*4+1].y, t0.y);
            t0.x = fmaf(p0.z, wg01[qq*4+2].x, t0.x); t0.y = fmaf(p0.z, wg01[qq*4+2].y, t0.y);
            t0.x = fmaf(p0.w, wg01[qq*4+3].x, t0.x); t0.y = fmaf(p0.w, wg01[qq*4+3].y, t0.y);
        }
        union { uint32 u; float f; } c0x, c0y;
        c0x.u = a0 << 16; c0y.u = a0 & 0xffff0000u;
        acc.x = fmaf(c0x.f, t0.x, acc.x); acc.y = fmaf(c0y.f, t0.y, acc.y);
    }
    *reinterpret_cast<float2*>(v + (size_t)i * DD + d0) = acc;
}

extern "C" void kernel_launch(void* const* d_in, const int* in_sizes, int n_in,
                              void* d_out, int out_size, void* d_ws, size_t ws_size,
                              hipStream_t stream)
{
    const float* x     = (const float*)d_in[0];
    const float* g     = (const float*)d_in[1];
    const int*   idx_i = (const int*)d_in[2];
    const int*   idx_j = (const int*)d_in[3];
    const float* u     = (const float*)d_in[5];
    const float* Wf    = (const float*)d_in[6];
    const float* bf    = (const float*)d_in[7];
    const float* Wg    = (const float*)d_in[8];
    const float* bg    = (const float*)d_in[9];
    const float* Wj    = (const float*)d_in[10];
    const float* bj    = (const float*)d_in[11];
    const float* Wi    = (const float*)d_in[12];
    const float* bi    = (const float*)d_in[13];
    const float* rw1   = (const float*)d_in[14];
    const float* rb1   = (const float*)d_in[15];
    const float* rw2   = (const float*)d_in[16];
    const float* rb2   = (const float*)d_in[17];

    const int N = in_sizes[0] / DD;   // 50000
    const int E = in_sizes[2];        // 640000
    float* out = (float*)d_out;

    // workspace layout
    float*          v     = (float*)d_ws;                           // [N,128] f32
    unsigned short* A     = (unsigned short*)(v + (size_t)N * DD);  // [N,128] bf16
    int*            cnt   = (int*)(A + (size_t)N * DD);
    int*            off   = cnt + N;
    int*            cnt2  = off + N;
    int2*           spair = (int2*)(cnt2 + N);                      // [E]
    unsigned short* Wb    = (unsigned short*)(spair + E);           // 9*16384 bf16

    dim3 blk(256);
    const int tiles   = (N + 63) / 64;
    const int eblocks = (E + 255) / 256;

    convert_w<<<72, blk, 0, stream>>>(Wj, Wi, rw1, rw2, Wf, Wb);

    hipMemsetAsync(cnt, 0, (size_t)N * sizeof(int), stream);
    hipMemsetAsync(cnt2, 0, (size_t)N * sizeof(int), stream);
    hist_kernel<<<eblocks, blk, 0, stream>>>(idx_i, cnt, E);
    scan_kernel<<<1, blk, 0, stream>>>(cnt, off, N);
    scatter_kernel<<<eblocks, blk, 0, stream>>>(idx_i, idx_j, off, cnt2, spair, E);

    dual_gemm<<<tiles, blk, 0, stream>>>(x, Wb, bj, bi, A, v, N);

    agg_kernel<<<(N + 3) / 4, blk, 0, stream>>>(off, cnt, spair, g, Wg, bg, A, v, N);

    tail_kernel<<<tiles, blk, 0, stream>>>(v, x, Wb, rb1, rb2, bf, u, out, N);
}